// Round 1
// baseline (525.850 us; speedup 1.0000x reference)
//
#include <hip/hip_runtime.h>

// DeformConv2dBlock: B=8, C=64, H=W=128, N=9 taps, pad=1 (padded 130x130 coords)

__device__ __forceinline__ float fetchx(const float* __restrict__ xb, int qx, int qy) {
    // qx,qy are PADDED coords in [0,129]; border ring is zero-pad
    if (qx < 1 || qx > 128 || qy < 1 || qy > 128) return 0.f;
    return xb[((qx - 1) << 7) + (qy - 1)];
}

// w_t[n][c][o] = w_conv[o][c][n]   (w_conv is (64,64,3,3), n = i*3+j)
__global__ void k_prep_wt(const float* __restrict__ w_conv, float* __restrict__ w_t) {
    int tid = blockIdx.x * 256 + threadIdx.x;
    if (tid >= 9 * 64 * 64) return;
    int o = tid & 63;
    int c = (tid >> 6) & 63;
    int n = tid >> 12;
    w_t[tid] = w_conv[(o * 64 + c) * 9 + n];
}

// offset conv: Conv2d(64 -> 18, 3x3, pad 1) + bias, output layout off_buf[pix][18]
__global__ __launch_bounds__(256) void k_offset(
    const float* __restrict__ x, const float* __restrict__ w_off,
    const float* __restrict__ b_off, float* __restrict__ off_buf) {
    __shared__ float xs[64][3][66];   // [c][row-1..row+1][wt-1..wt+64]
    const int gb = blockIdx.x;
    const int wt = (gb & 1) << 6;
    const int h  = (gb >> 1) & 127;
    const int b  = gb >> 8;

    for (int idx = threadIdx.x; idx < 64 * 3 * 66; idx += 256) {
        int c  = idx / 198;
        int rj = idx - c * 198;
        int r  = rj / 66;
        int j  = rj - r * 66;
        int row = h + r - 1;
        int col = wt + j - 1;
        float v = 0.f;
        if (row >= 0 && row < 128 && col >= 0 && col < 128)
            v = x[((b * 64 + c) * 128 + row) * 128 + col];
        xs[c][r][j] = v;
    }
    __syncthreads();

    const int p  = threadIdx.x & 63;   // pixel within row tile (lane)
    const int kq = threadIdx.x >> 6;   // wave id -> k residue class
    float acc[5];
    int   kb[5];
    bool  kv[5];
#pragma unroll
    for (int m = 0; m < 5; ++m) {
        int k = kq + 4 * m;
        kv[m] = (k < 18);
        int kk = kv[m] ? k : 0;
        kb[m]  = __builtin_amdgcn_readfirstlane(kk) * 576;  // wave-uniform -> s_load path
        acc[m] = kv[m] ? b_off[kk] : 0.f;
    }
    for (int c = 0; c < 64; ++c) {
#pragma unroll
        for (int r = 0; r < 3; ++r) {
#pragma unroll
            for (int j = 0; j < 3; ++j) {
                float v = xs[c][r][p + j];
                int wbase = (c * 3 + r) * 3 + j;
#pragma unroll
                for (int m = 0; m < 5; ++m)
                    acc[m] += v * w_off[kb[m] + wbase];
            }
        }
    }
    const int pix = (b * 128 + h) * 128 + wt + p;
#pragma unroll
    for (int m = 0; m < 5; ++m)
        if (kv[m]) off_buf[pix * 18 + kq + 4 * m] = acc[m];
}

// main: fused bilinear gather + GEMM (64 pixels x 64 outputs per block) + residual
__global__ __launch_bounds__(256) void k_main(
    const float* __restrict__ x, const float* __restrict__ off_buf,
    const float* __restrict__ w_t, float* __restrict__ out) {
    __shared__ int4   qtab[576];     // [p*9+n] = (qlt_x, qrb_x, qlt_y, qrb_y)
    __shared__ float4 gtab[576];     // [p*9+n] = (g_lt, g_rb, g_lb, g_rt)
    __shared__ float  As[64 * 64];   // [c][p]
    __shared__ float  Bs[64 * 64];   // [c][o]

    const int gb = blockIdx.x;
    const int wt = (gb & 1) << 6;
    const int h  = (gb >> 1) & 127;
    const int b  = gb >> 8;

    // phase 0: per (pixel, n) sampling indices & bilinear weights
    for (int idx = threadIdx.x; idx < 576; idx += 256) {
        int p = idx / 9;
        int n = idx - p * 9;
        int pix = (b * 128 + h) * 128 + wt + p;
        float ox = off_buf[pix * 18 + n];
        float oy = off_buf[pix * 18 + 9 + n];
        float px = ox + (float)(n / 3 - 1) + (float)(h + 1);
        float py = oy + (float)(n % 3 - 1) + (float)(wt + p + 1);
        float fx = floorf(px), fy = floorf(py);
        int qltx = (int)fminf(fmaxf(fx, 0.f), 129.f);
        int qlty = (int)fminf(fmaxf(fy, 0.f), 129.f);
        int qrbx = (int)fminf(fmaxf(fx + 1.f, 0.f), 129.f);
        int qrby = (int)fminf(fmaxf(fy + 1.f, 0.f), 129.f);
        px = fminf(fmaxf(px, 0.f), 129.f);
        py = fminf(fmaxf(py, 0.f), 129.f);
        float glt = (1.f + ((float)qltx - px)) * (1.f + ((float)qlty - py));
        float grb = (1.f - ((float)qrbx - px)) * (1.f - ((float)qrby - py));
        float glb = (1.f + ((float)qltx - px)) * (1.f - ((float)qrby - py));
        float grt = (1.f - ((float)qrbx - px)) * (1.f + ((float)qlty - py));
        qtab[idx] = make_int4(qltx, qrbx, qlty, qrby);
        gtab[idx] = make_float4(glt, grb, glb, grt);
    }
    __syncthreads();

    float acc[4][4];   // [o_j][p_i]
#pragma unroll
    for (int j = 0; j < 4; ++j)
#pragma unroll
        for (int i = 0; i < 4; ++i) acc[j][i] = 0.f;

    const int p   = threadIdx.x & 63;  // gather: pixel lane
    const int cb  = threadIdx.x >> 6;  // gather: channel quarter
    const int tro = threadIdx.x >> 4;  // compute: o-group (o0 = tro*4)
    const int tcp = threadIdx.x & 15;  // compute: p-group (p0 = tcp*4)

    for (int n = 0; n < 9; ++n) {
        __syncthreads();   // previous compute done before overwriting As/Bs
        // stage Bs = w_t[n][c][o]
        {
            const float4* src = (const float4*)(w_t + (n << 12));
            float4* dst = (float4*)Bs;
#pragma unroll
            for (int i = 0; i < 4; ++i)
                dst[threadIdx.x + (i << 8)] = src[threadIdx.x + (i << 8)];
        }
        // gather As[c][p] = bilinear sample of channel c at tap n of pixel p
        {
            int ti = p * 9 + n;
            int4   q = qtab[ti];
            float4 g = gtab[ti];
            const float* xb0 = x + ((size_t)(b * 64 + cb * 16) << 14);
#pragma unroll 4
            for (int cc = 0; cc < 16; ++cc) {
                const float* xb = xb0 + ((size_t)cc << 14);
                float v = g.x * fetchx(xb, q.x, q.z)
                        + g.y * fetchx(xb, q.y, q.w)
                        + g.z * fetchx(xb, q.x, q.w)
                        + g.w * fetchx(xb, q.y, q.z);
                As[(cb * 16 + cc) * 64 + p] = v;
            }
        }
        __syncthreads();
        // compute: acc[o][p] += sum_c As[c][p] * Bs[c][o]
#pragma unroll 8
        for (int c = 0; c < 64; ++c) {
            float4 a  = *(const float4*)&As[c * 64 + tcp * 4];
            float4 bv = *(const float4*)&Bs[c * 64 + tro * 4];
            acc[0][0] += bv.x * a.x; acc[0][1] += bv.x * a.y; acc[0][2] += bv.x * a.z; acc[0][3] += bv.x * a.w;
            acc[1][0] += bv.y * a.x; acc[1][1] += bv.y * a.y; acc[1][2] += bv.y * a.z; acc[1][3] += bv.y * a.w;
            acc[2][0] += bv.z * a.x; acc[2][1] += bv.z * a.y; acc[2][2] += bv.z * a.z; acc[2][3] += bv.z * a.w;
            acc[3][0] += bv.w * a.x; acc[3][1] += bv.w * a.y; acc[3][2] += bv.w * a.z; acc[3][3] += bv.w * a.w;
        }
    }

    // epilogue: out = gemm + x (residual), float4 coalesced
#pragma unroll
    for (int j = 0; j < 4; ++j) {
        int o = tro * 4 + j;
        size_t base = (((size_t)(b * 64 + o) * 128 + h) * 128) + wt + tcp * 4;
        float4 xv = *(const float4*)(x + base);
        float4 ov = make_float4(acc[j][0] + xv.x, acc[j][1] + xv.y,
                                acc[j][2] + xv.z, acc[j][3] + xv.w);
        *(float4*)(out + base) = ov;
    }
}

extern "C" void kernel_launch(void* const* d_in, const int* in_sizes, int n_in,
                              void* d_out, int out_size, void* d_ws, size_t ws_size,
                              hipStream_t stream) {
    const float* x      = (const float*)d_in[0];
    const float* w_off  = (const float*)d_in[1];
    const float* b_off  = (const float*)d_in[2];
    const float* w_conv = (const float*)d_in[3];
    float* out = (float*)d_out;

    // ws: off_buf (8*128*128*18 f32 = 9.44 MB) | w_t (9*64*64 f32 = 147 KB)
    float* off_buf = (float*)d_ws;
    float* w_t     = off_buf + (size_t)8 * 128 * 128 * 18;

    hipLaunchKernelGGL(k_prep_wt, dim3(144),  dim3(256), 0, stream, w_conv, w_t);
    hipLaunchKernelGGL(k_offset,  dim3(2048), dim3(256), 0, stream, x, w_off, b_off, off_buf);
    hipLaunchKernelGGL(k_main,    dim3(2048), dim3(256), 0, stream, x, off_buf, w_t, out);
}

// Round 2
// 187.808 us; speedup vs baseline: 2.7999x; 2.7999x over previous
//
#include <hip/hip_runtime.h>

// DeformConv2dBlock on gfx950: B=8, C=64, H=W=128, N=9 taps, pad=1.
// Pipeline: k_prep_xt (x -> channel-last bf16 xt), k_prep_w (bf16 weights),
// k_fused (offset conv MFMA -> bilinear tables -> gather + MFMA GEMM + residual).

typedef short bf16x8 __attribute__((ext_vector_type(8)));
typedef float f32x4  __attribute__((ext_vector_type(4)));

#define MFMA16(a, b, c) __builtin_amdgcn_mfma_f32_16x16x32_bf16(a, b, c, 0, 0, 0)

__device__ __forceinline__ float bflo(unsigned w) { return __builtin_bit_cast(float, w << 16); }
__device__ __forceinline__ float bfhi(unsigned w) { return __builtin_bit_cast(float, w & 0xffff0000u); }
__device__ __forceinline__ unsigned short f2bf(float f) {   // RNE
    unsigned u = __builtin_bit_cast(unsigned, f);
    u += 0x7fffu + ((u >> 16) & 1u);
    return (unsigned short)(u >> 16);
}

// x[b][c][h][w] f32 -> xt[b][h][w][c] bf16
__global__ __launch_bounds__(256) void k_prep_xt(const float* __restrict__ x,
                                                 unsigned short* __restrict__ xt) {
    __shared__ float xs[64][129];
    const int bh = blockIdx.x;            // b*128 + h
    const int h = bh & 127, b = bh >> 7;
    const float* xr = x + ((size_t)b * 64 * 128 + h) * 128;
    for (int idx = threadIdx.x; idx < 8192; idx += 256) {
        int c = idx >> 7, w = idx & 127;
        xs[c][w] = xr[(size_t)c * 16384 + w];
    }
    __syncthreads();
    unsigned short* xto = xt + ((size_t)bh << 13);   // bh * 128 * 64
    for (int j = threadIdx.x; j < 1024; j += 256) {
        int w = j >> 3, c0 = (j & 7) << 3;
        unsigned short tmp[8];
#pragma unroll
        for (int e = 0; e < 8; ++e) tmp[e] = f2bf(xs[c0 + e][w]);
        *(uint4*)(xto + w * 64 + c0) = *(const uint4*)tmp;
    }
}

// w_m[n][o][c] = bf16(w_conv[o][c][n]);  woff_m[rj][k][c] = bf16(w_off[k][c][rj]) (k<18, else 0)
__global__ void k_prep_w(const float* __restrict__ w_conv, const float* __restrict__ w_off,
                         unsigned short* __restrict__ w_m, unsigned short* __restrict__ woff_m) {
    int t = blockIdx.x * 256 + threadIdx.x;
    if (t < 36864) {
        int n = t >> 12, rem = t & 4095, o = rem >> 6, c = rem & 63;
        w_m[t] = f2bf(w_conv[(o * 64 + c) * 9 + n]);
    }
    int t2 = t - 36864;
    if (t2 >= 0 && t2 < 18432) {
        int rj = t2 >> 11, rem = t2 & 2047, k = rem >> 6, c = rem & 63;
        woff_m[t2] = (k < 18) ? f2bf(w_off[(k * 64 + c) * 9 + rj]) : (unsigned short)0;
    }
}

// One block = (b, h, wt): 64 pixels x 64 output channels. 4 waves.
__global__ __launch_bounds__(256, 4) void k_fused(
    const float* __restrict__ x, const unsigned short* __restrict__ xt,
    const unsigned short* __restrict__ w_m, const unsigned short* __restrict__ woff_m,
    const float* __restrict__ b_off, float* __restrict__ out) {

    __shared__ int   atab[9][64][4];    // per (tap, pixel): 4 corner element-offsets into xt (0 if invalid)
    __shared__ float gtab[9][64][4];    // per (tap, pixel): 4 bilinear weights (0 if invalid)
    __shared__ __align__(16) unsigned char ubuf[16384];   // phase A: offv[64][20] f32; phase C: As[2][64][64] bf16 (swizzled)
    float* offv = (float*)ubuf;

    // XCD-contiguous work swizzle: each XCD (blockIdx%8) gets one full batch image
    const int wk = ((blockIdx.x & 7) << 8) + (blockIdx.x >> 3);
    const int b = wk >> 8, h = (wk >> 1) & 127, wt = (wk & 1) << 6;

    const int tid  = threadIdx.x;
    const int lane = tid & 63, wid = tid >> 6;
    const int l15  = lane & 15, q4 = lane >> 4;
    const int k0   = q4 << 3;

    const unsigned short* xtb = xt + ((size_t)b << 20);   // b*128*128*64

    // ---------------- Phase A: offset conv via MFMA (D[o][p] = Woff . X) ----------------
    {
        f32x4 oacc0 = {0.f, 0.f, 0.f, 0.f};
        f32x4 oacc1 = {0.f, 0.f, 0.f, 0.f};
        const int colbase = wt + wid * 16 + l15 - 1;
        for (int rj = 0; rj < 9; ++rj) {
            const int row = h + rj / 3 - 1;
            if (row < 0 || row > 127) continue;
            const int col = colbase + rj % 3;
            const bool cv = (col >= 0 && col < 128);
            const unsigned short* xrow = xtb + (((size_t)row << 7) + (cv ? col : 0)) * 64;
#pragma unroll
            for (int kc = 0; kc < 2; ++kc) {
                bf16x8 bv = {0, 0, 0, 0, 0, 0, 0, 0};
                if (cv) bv = *(const bf16x8*)(xrow + kc * 32 + k0);
                bf16x8 a0 = *(const bf16x8*)(woff_m + (rj * 32 + l15) * 64 + kc * 32 + k0);
                bf16x8 a1 = *(const bf16x8*)(woff_m + (rj * 32 + 16 + l15) * 64 + kc * 32 + k0);
                oacc0 = MFMA16(a0, bv, oacc0);
                oacc1 = MFMA16(a1, bv, oacc1);
            }
        }
        // D: col(lane&15)=pixel, row((lane>>4)*4+reg)=o.  offv[p][o] = conv + bias
        const int p = wid * 16 + l15;
#pragma unroll
        for (int rg = 0; rg < 4; ++rg) {
            int o = q4 * 4 + rg;
            offv[p * 20 + o] = oacc0[rg] + b_off[o];           // o in [0,16)
            int o1 = 16 + o;
            if (o1 < 18) offv[p * 20 + o1] = oacc1[rg] + b_off[o1];
        }
    }
    __syncthreads();

    // ---------------- Phase B: bilinear corner addresses + weights ----------------
    for (int idx = tid; idx < 576; idx += 256) {
        const int n = idx >> 6, p = idx & 63;
        float ox = offv[p * 20 + n], oy = offv[p * 20 + 9 + n];
        float px = ox + (float)(n / 3 - 1) + (float)(h + 1);
        float py = oy + (float)(n % 3 - 1) + (float)(wt + p + 1);
        float fx = floorf(px), fy = floorf(py);
        float fxc  = fminf(fmaxf(fx, 0.f), 129.f);
        float fyc  = fminf(fmaxf(fy, 0.f), 129.f);
        float fxc1 = fminf(fmaxf(fx + 1.f, 0.f), 129.f);
        float fyc1 = fminf(fmaxf(fy + 1.f, 0.f), 129.f);
        int qltx = (int)fxc, qlty = (int)fyc, qrbx = (int)fxc1, qrby = (int)fyc1;
        px = fminf(fmaxf(px, 0.f), 129.f);
        py = fminf(fmaxf(py, 0.f), 129.f);
        float glt = (1.f + (fxc  - px)) * (1.f + (fyc  - py));
        float grb = (1.f - (fxc1 - px)) * (1.f - (fyc1 - py));
        float glb = (1.f + (fxc  - px)) * (1.f - (fyc1 - py));
        float grt = (1.f - (fxc1 - px)) * (1.f + (fyc  - py));
        bool vlx = (qltx >= 1) & (qltx <= 128), vly = (qlty >= 1) & (qlty <= 128);
        bool vrx = (qrbx >= 1) & (qrbx <= 128), vry = (qrby >= 1) & (qrby <= 128);
        int a0 = (vlx & vly) ? ((((qltx - 1) << 7) + (qlty - 1)) << 6) : 0;
        int a1 = (vrx & vry) ? ((((qrbx - 1) << 7) + (qrby - 1)) << 6) : 0;
        int a2 = (vlx & vry) ? ((((qltx - 1) << 7) + (qrby - 1)) << 6) : 0;
        int a3 = (vrx & vly) ? ((((qrbx - 1) << 7) + (qlty - 1)) << 6) : 0;
        if (!(vlx & vly)) glt = 0.f;
        if (!(vrx & vry)) grb = 0.f;
        if (!(vlx & vry)) glb = 0.f;
        if (!(vrx & vly)) grt = 0.f;
        *(int4*)&atab[n][p][0]   = make_int4(a0, a1, a2, a3);
        *(float4*)&gtab[n][p][0] = make_float4(glt, grb, glb, grt);
    }
    __syncthreads();

    // ---------------- Phase C: gather (bf16, XOR-swizzled LDS) + MFMA GEMM ----------------
    // gather role: lane = pixel, wid = 16-channel group. As[buf][p][c] bf16, slot ^= (p&7).
    auto do_gather = [&](int nn, int buf) {
        const int4   av = *(const int4*)&atab[nn][lane][0];
        const float4 gv = *(const float4*)&gtab[nn][lane][0];
#pragma unroll
        for (int g8 = 0; g8 < 2; ++g8) {
            const int c0 = (wid << 4) + (g8 << 3);
            uint4 w0 = *(const uint4*)(xtb + av.x + c0);
            uint4 w1 = *(const uint4*)(xtb + av.y + c0);
            uint4 w2 = *(const uint4*)(xtb + av.z + c0);
            uint4 w3 = *(const uint4*)(xtb + av.w + c0);
            unsigned ow[4];
#define BLEND(U0, U1, U2, U3, K)                                                          \
            {                                                                             \
                float lo = gv.x * bflo(U0) + gv.y * bflo(U1) + gv.z * bflo(U2) + gv.w * bflo(U3); \
                float hi = gv.x * bfhi(U0) + gv.y * bfhi(U1) + gv.z * bfhi(U2) + gv.w * bfhi(U3); \
                ow[K] = (unsigned)f2bf(lo) | ((unsigned)f2bf(hi) << 16);                  \
            }
            BLEND(w0.x, w1.x, w2.x, w3.x, 0)
            BLEND(w0.y, w1.y, w2.y, w3.y, 1)
            BLEND(w0.z, w1.z, w2.z, w3.z, 2)
            BLEND(w0.w, w1.w, w2.w, w3.w, 3)
#undef BLEND
            const int slot = (c0 >> 3) ^ (lane & 7);
            *(uint4*)(ubuf + buf * 8192 + lane * 128 + slot * 16) = make_uint4(ow[0], ow[1], ow[2], ow[3]);
        }
    };

    f32x4 acc[4];
#pragma unroll
    for (int of = 0; of < 4; ++of) acc[of] = (f32x4){0.f, 0.f, 0.f, 0.f};

    do_gather(0, 0);
    __syncthreads();

    for (int n = 0; n < 9; ++n) {
        if (n < 8) do_gather(n + 1, (n + 1) & 1);
        // B fragments: lane reads As[p = wid*16 + l15][k-chunk], swizzled
        const unsigned char* ab = ubuf + (n & 1) * 8192 + (wid * 16 + l15) * 128;
        bf16x8 bfr0 = *(const bf16x8*)(ab + (((0 * 4 + q4) ^ (l15 & 7)) << 4));
        bf16x8 bfr1 = *(const bf16x8*)(ab + (((1 * 4 + q4) ^ (l15 & 7)) << 4));
        const unsigned short* wn = w_m + n * 4096;
#pragma unroll
        for (int of = 0; of < 4; ++of) {
            bf16x8 af0 = *(const bf16x8*)(wn + (of * 16 + l15) * 64 + 0 * 32 + k0);
            bf16x8 af1 = *(const bf16x8*)(wn + (of * 16 + l15) * 64 + 1 * 32 + k0);
            acc[of] = MFMA16(af0, bfr0, acc[of]);
            acc[of] = MFMA16(af1, bfr1, acc[of]);
        }
        __syncthreads();
    }

    // ---------------- Epilogue: D[o][p], o = of*16 + q4*4 + rg, p = wid*16 + l15 ----------------
    const size_t obase = ((size_t)b * 64 * 128 + h) * 128 + wt + wid * 16 + l15;
#pragma unroll
    for (int of = 0; of < 4; ++of) {
#pragma unroll
        for (int rg = 0; rg < 4; ++rg) {
            size_t a = obase + (size_t)(of * 16 + q4 * 4 + rg) * 16384;
            out[a] = acc[of][rg] + x[a];
        }
    }
}

extern "C" void kernel_launch(void* const* d_in, const int* in_sizes, int n_in,
                              void* d_out, int out_size, void* d_ws, size_t ws_size,
                              hipStream_t stream) {
    const float* x      = (const float*)d_in[0];
    const float* w_off  = (const float*)d_in[1];
    const float* b_off  = (const float*)d_in[2];
    const float* w_conv = (const float*)d_in[3];

    // ws: xt bf16 (16.78 MB) | w_m bf16 (72 KB) | woff_m bf16 (36 KB)
    unsigned short* xt     = (unsigned short*)d_ws;
    unsigned short* w_m    = xt + (size_t)8 * 128 * 128 * 64;
    unsigned short* woff_m = w_m + 9 * 64 * 64;

    hipLaunchKernelGGL(k_prep_xt, dim3(1024), dim3(256), 0, stream, x, xt);
    hipLaunchKernelGGL(k_prep_w,  dim3(216),  dim3(256), 0, stream, w_conv, w_off, w_m, woff_m);
    hipLaunchKernelGGL(k_fused,   dim3(2048), dim3(256), 0, stream,
                       x, xt, w_m, woff_m, b_off, (float*)d_out);
}

// Round 3
// 101.902 us; speedup vs baseline: 5.1604x; 1.8430x over previous
//
#include <hip/hip_runtime.h>

// DeformConv2dBlock on gfx950: B=8, C=64, H=W=128, N=9 taps, pad=1.
// R2: persistent swizzled LDS window per 64-px row tile; barrier-free tap loop;
// fragment-ordered bf16 weights (coalesced 1KB wave loads); global fallback for
// out-of-window samples (tagged addresses).

typedef short bf16x8 __attribute__((ext_vector_type(8)));
typedef float f32x4  __attribute__((ext_vector_type(4)));

#define MFMA16(a, b, c) __builtin_amdgcn_mfma_f32_16x16x32_bf16(a, b, c, 0, 0, 0)
#define GTAG 0x40000000

__device__ __forceinline__ float bflo(unsigned w) { return __builtin_bit_cast(float, w << 16); }
__device__ __forceinline__ float bfhi(unsigned w) { return __builtin_bit_cast(float, w & 0xffff0000u); }
__device__ __forceinline__ unsigned short f2bf(float f) {   // RNE
    unsigned u = __builtin_bit_cast(unsigned, f);
    u += 0x7fffu + ((u >> 16) & 1u);
    return (unsigned short)(u >> 16);
}

// x[b][c][h][w] f32 -> xt[b][h][w][c] bf16
__global__ __launch_bounds__(256) void k_prep_xt(const float* __restrict__ x,
                                                 unsigned short* __restrict__ xt) {
    __shared__ float xs[64][129];
    const int bh = blockIdx.x;            // b*128 + h
    const int h = bh & 127, b = bh >> 7;
    const float* xr = x + ((size_t)b * 64 * 128 + h) * 128;
    for (int idx = threadIdx.x; idx < 8192; idx += 256) {
        int c = idx >> 7, w = idx & 127;
        xs[c][w] = xr[(size_t)c * 16384 + w];
    }
    __syncthreads();
    unsigned short* xto = xt + ((size_t)bh << 13);
    for (int j = threadIdx.x; j < 1024; j += 256) {
        int w = j >> 3, c0 = (j & 7) << 3;
        unsigned short tmp[8];
#pragma unroll
        for (int e = 0; e < 8; ++e) tmp[e] = f2bf(xs[c0 + e][w]);
        *(uint4*)(xto + w * 64 + c0) = *(const uint4*)tmp;
    }
}

// Fragment-ordered weights.
// w_m2:  frag id = (n*4 + of)*2 + chunk; within frag lane (l15,q4) at (l15*4+q4)*8.
//        element (o = of*16+l15, c = chunk*32+q4*8+e, tap n).
// woff2: frag id = (rj*2 + half)*2 + kc; element (k = half*16+l15, c = kc*32+q4*8+e, tap rj).
__global__ void k_prep_w(const float* __restrict__ w_conv, const float* __restrict__ w_off,
                         unsigned short* __restrict__ w_m2, unsigned short* __restrict__ woff2) {
    int t = blockIdx.x * 256 + threadIdx.x;
    if (t < 36864) {
        int r = t & 511;
        int fid = t >> 9;
        int l15 = r >> 5, q4 = (r >> 3) & 3, e = t & 7;
        int chunk = fid & 1, of = (fid >> 1) & 3, n = fid >> 3;
        int o = of * 16 + l15, c = chunk * 32 + q4 * 8 + e;
        w_m2[t] = f2bf(w_conv[(o * 64 + c) * 9 + n]);
    }
    int t2 = t - 36864;
    if (t2 >= 0 && t2 < 18432) {
        int r = t2 & 511;
        int fid = t2 >> 9;
        int l15 = r >> 5, q4 = (r >> 3) & 3, e = t2 & 7;
        int kc = fid & 1, half = (fid >> 1) & 1, rj = fid >> 2;
        int k = half * 16 + l15, c = kc * 32 + q4 * 8 + e;
        woff2[t2] = (k < 18) ? f2bf(w_off[(k * 64 + c) * 9 + rj]) : (unsigned short)0;
    }
}

// One block = (b, h, wt): 64 pixels x 64 output channels. 4 waves.
__global__ __launch_bounds__(256, 2) void k_fused(
    const float* __restrict__ x, const unsigned short* __restrict__ xt,
    const unsigned short* __restrict__ w_m2, const unsigned short* __restrict__ woff2,
    const float* __restrict__ b_off, float* __restrict__ out) {

    __shared__ __align__(16) unsigned char raw[420 * 128];   // window: 6 rows x 70 cols x 64ch bf16, swizzled
    __shared__ int   atab[9][64][4];
    __shared__ float gtab[9][64][4];
    __shared__ float offv[64 * 20];

    const int wk = ((blockIdx.x & 7) << 8) + (blockIdx.x >> 3);   // XCD swizzle
    const int b = wk >> 8, h = (wk >> 1) & 127, wt = (wk & 1) << 6;

    const int tid  = threadIdx.x;
    const int lane = tid & 63, wid = tid >> 6;
    const int l15  = lane & 15, q4 = lane >> 4;
    const int lofs = ((l15 << 2) + q4) << 3;   // lane's element offset within a 1KB frag
    const int px   = wid * 16 + l15;

    const unsigned short* xtb = xt + ((size_t)b << 20);

    // ---- stage window: xt rows [h-2, h+3], cols [wt-3, wt+66], zero-filled, swizzled ----
    for (int idx = tid; idx < 3360; idx += 256) {
        int rec = idx >> 3, cc = idx & 7;
        int row = rec / 70, col = rec - row * 70;
        int xr = h - 2 + row, xc = wt - 3 + col;
        uint4 v = make_uint4(0, 0, 0, 0);
        if (xr >= 0 && xr < 128 && xc >= 0 && xc < 128)
            v = *(const uint4*)(xtb + ((((size_t)xr << 7) + xc) << 6) + (cc << 3));
        *(uint4*)(raw + (rec << 7) + ((cc ^ (col & 7)) << 4)) = v;
    }
    __syncthreads();

    // ---- Phase A: offset conv via MFMA, B-fragments from LDS window ----
    {
        f32x4 o0 = {0.f, 0.f, 0.f, 0.f}, o1 = {0.f, 0.f, 0.f, 0.f};
        for (int rj = 0; rj < 9; ++rj) {
            const int dr = rj / 3, dj = rj % 3;          // input row h+dr-1, col wt+px+dj-1
            const int colw = px + dj + 2;                // window col index
            const int recb = (dr + 1) * 70 + colw;
            const int swz  = colw & 7;
#pragma unroll
            for (int kc = 0; kc < 2; ++kc) {
                bf16x8 bfrag = *(const bf16x8*)(raw + (recb << 7) + ((((kc << 2) + q4) ^ swz) << 4));
                bf16x8 a0 = *(const bf16x8*)(woff2 + ((((rj * 2 + 0) << 1) + kc) << 9) + lofs);
                bf16x8 a1 = *(const bf16x8*)(woff2 + ((((rj * 2 + 1) << 1) + kc) << 9) + lofs);
                o0 = MFMA16(a0, bfrag, o0);
                o1 = MFMA16(a1, bfrag, o1);
            }
        }
#pragma unroll
        for (int rg = 0; rg < 4; ++rg) {
            int o = q4 * 4 + rg;
            offv[px * 20 + o] = o0[rg] + b_off[o];
            int o1i = 16 + o;
            if (o1i < 18) offv[px * 20 + o1i] = o1[rg] + b_off[o1i];
        }
    }
    __syncthreads();

    // ---- Phase B: bilinear corner entries (LDS window offset or tagged global) + weights ----
    for (int idx = tid; idx < 576; idx += 256) {
        const int n = idx >> 6, p = idx & 63;
        float ox = offv[p * 20 + n], oy = offv[p * 20 + 9 + n];
        float pxf = ox + (float)(n / 3 - 1) + (float)(h + 1);
        float pyf = oy + (float)(n % 3 - 1) + (float)(wt + p + 1);
        float fx = floorf(pxf), fy = floorf(pyf);
        float fxc  = fminf(fmaxf(fx, 0.f), 129.f);
        float fyc  = fminf(fmaxf(fy, 0.f), 129.f);
        float fxc1 = fminf(fmaxf(fx + 1.f, 0.f), 129.f);
        float fyc1 = fminf(fmaxf(fy + 1.f, 0.f), 129.f);
        int qltx = (int)fxc, qlty = (int)fyc, qrbx = (int)fxc1, qrby = (int)fyc1;
        pxf = fminf(fmaxf(pxf, 0.f), 129.f);
        pyf = fminf(fmaxf(pyf, 0.f), 129.f);
        float glt = (1.f + (fxc  - pxf)) * (1.f + (fyc  - pyf));
        float grb = (1.f - (fxc1 - pxf)) * (1.f - (fyc1 - pyf));
        float glb = (1.f + (fxc  - pxf)) * (1.f - (fyc1 - pyf));
        float grt = (1.f - (fxc1 - pxf)) * (1.f + (fyc  - pyf));
        bool vlx = (qltx >= 1) & (qltx <= 128), vly = (qlty >= 1) & (qlty <= 128);
        bool vrx = (qrbx >= 1) & (qrbx <= 128), vry = (qrby >= 1) & (qrby <= 128);

        auto enc = [&](int qx, int qy, bool val) -> int {
            if (!val) return 0;                       // g forced to 0
            int wr = qx - h + 1;                      // (qx-1) - (h-2)
            int wc = qy - wt + 2;                     // (qy-1) - (wt-3)
            if (wr >= 0 && wr < 6 && wc >= 0 && wc < 70)
                return ((wr * 70 + wc) << 7) | ((wc & 7) << 4);
            return GTAG | ((((qx - 1) << 7) + (qy - 1)) << 6);
        };
        int a0 = enc(qltx, qlty, vlx & vly);
        int a1 = enc(qrbx, qrby, vrx & vry);
        int a2 = enc(qltx, qrby, vlx & vry);
        int a3 = enc(qrbx, qlty, vrx & vly);
        if (!(vlx & vly)) glt = 0.f;
        if (!(vrx & vry)) grb = 0.f;
        if (!(vlx & vry)) glb = 0.f;
        if (!(vrx & vly)) grt = 0.f;
        *(int4*)&atab[n][p][0]   = make_int4(a0, a1, a2, a3);
        *(float4*)&gtab[n][p][0] = make_float4(glt, grb, glb, grt);
    }
    __syncthreads();

    // ---- Phase C: barrier-free tap loop; blend -> register B-fragments -> MFMA ----
    f32x4 acc[4];
#pragma unroll
    for (int of = 0; of < 4; ++of) acc[of] = (f32x4){0.f, 0.f, 0.f, 0.f};

    for (int n = 0; n < 9; ++n) {
        const int4   av = *(const int4*)&atab[n][px][0];
        const float4 gv = *(const float4*)&gtab[n][px][0];

        uint4 clo[4], chi[4];
        const int ee[4] = {av.x, av.y, av.z, av.w};
#pragma unroll
        for (int j = 0; j < 4; ++j) {
            int e = ee[j];
            if (e & GTAG) {
                const unsigned short* gp = xtb + (e & (GTAG - 1));
                clo[j] = *(const uint4*)(gp + (q4 << 3));
                chi[j] = *(const uint4*)(gp + (q4 << 3) + 32);
            } else {
                const unsigned char* lp = raw + (e & ~127);
                int sl = ((q4 ^ (e >> 4)) & 7) << 4;
                clo[j] = *(const uint4*)(lp + sl);
                chi[j] = *(const uint4*)(lp + (sl ^ 64));
            }
        }

        bf16x8 bfr0, bfr1;
        {
            const unsigned* p0 = (const unsigned*)&clo[0];
            const unsigned* p1 = (const unsigned*)&clo[1];
            const unsigned* p2 = (const unsigned*)&clo[2];
            const unsigned* p3 = (const unsigned*)&clo[3];
            const unsigned* h0 = (const unsigned*)&chi[0];
            const unsigned* h1 = (const unsigned*)&chi[1];
            const unsigned* h2 = (const unsigned*)&chi[2];
            const unsigned* h3 = (const unsigned*)&chi[3];
            unsigned owl[4], owh[4];
#pragma unroll
            for (int d = 0; d < 4; ++d) {
                float flo = gv.x * bflo(p0[d]) + gv.y * bflo(p1[d]) + gv.z * bflo(p2[d]) + gv.w * bflo(p3[d]);
                float fhi = gv.x * bfhi(p0[d]) + gv.y * bfhi(p1[d]) + gv.z * bfhi(p2[d]) + gv.w * bfhi(p3[d]);
                owl[d] = (unsigned)f2bf(flo) | ((unsigned)f2bf(fhi) << 16);
                float glo = gv.x * bflo(h0[d]) + gv.y * bflo(h1[d]) + gv.z * bflo(h2[d]) + gv.w * bflo(h3[d]);
                float ghi = gv.x * bfhi(h0[d]) + gv.y * bfhi(h1[d]) + gv.z * bfhi(h2[d]) + gv.w * bfhi(h3[d]);
                owh[d] = (unsigned)f2bf(glo) | ((unsigned)f2bf(ghi) << 16);
            }
            bfr0 = *(const bf16x8*)&owl[0];
            bfr1 = *(const bf16x8*)&owh[0];
        }

        const unsigned short* wn = w_m2 + (n << 12);
#pragma unroll
        for (int of = 0; of < 4; ++of) {
            bf16x8 a0 = *(const bf16x8*)(wn + (((of << 1) + 0) << 9) + lofs);
            bf16x8 a1 = *(const bf16x8*)(wn + (((of << 1) + 1) << 9) + lofs);
            acc[of] = MFMA16(a0, bfr0, acc[of]);
            acc[of] = MFMA16(a1, bfr1, acc[of]);
        }
    }

    // ---- Epilogue: D col = px, row = of*16 + q4*4 + rg; + residual ----
    const size_t obase = ((size_t)b * 64 * 128 + h) * 128 + wt + px;
#pragma unroll
    for (int of = 0; of < 4; ++of) {
#pragma unroll
        for (int rg = 0; rg < 4; ++rg) {
            size_t a = obase + (size_t)(of * 16 + q4 * 4 + rg) * 16384;
            out[a] = acc[of][rg] + x[a];
        }
    }
}

extern "C" void kernel_launch(void* const* d_in, const int* in_sizes, int n_in,
                              void* d_out, int out_size, void* d_ws, size_t ws_size,
                              hipStream_t stream) {
    const float* x      = (const float*)d_in[0];
    const float* w_off  = (const float*)d_in[1];
    const float* b_off  = (const float*)d_in[2];
    const float* w_conv = (const float*)d_in[3];

    // ws: xt bf16 (16.78 MB) | w_m2 bf16 (72 KB) | woff2 bf16 (36 KB)
    unsigned short* xt    = (unsigned short*)d_ws;
    unsigned short* w_m2  = xt + (size_t)8 * 128 * 128 * 64;
    unsigned short* woff2 = w_m2 + 9 * 64 * 64;

    hipLaunchKernelGGL(k_prep_xt, dim3(1024), dim3(256), 0, stream, x, xt);
    hipLaunchKernelGGL(k_prep_w,  dim3(216),  dim3(256), 0, stream, w_conv, w_off, w_m2, woff2);
    hipLaunchKernelGGL(k_fused,   dim3(2048), dim3(256), 0, stream,
                       x, xt, w_m2, woff2, b_off, (float*)d_out);
}

// Round 4
// 97.417 us; speedup vs baseline: 5.3979x; 1.0460x over previous
//
#include <hip/hip_runtime.h>

// DeformConv2dBlock on gfx950: B=8, C=64, H=W=128, N=9 taps, pad=1.
// R3: block-uniform fast path (zero-branch unrolled tap loop), v_perm bf16 pack,
// residual prefetch, offv stride pad. Window/tables structure from R2.

typedef short bf16x8 __attribute__((ext_vector_type(8)));
typedef float f32x4  __attribute__((ext_vector_type(4)));

#define MFMA16(a, b, c) __builtin_amdgcn_mfma_f32_16x16x32_bf16(a, b, c, 0, 0, 0)
#define GTAG 0x40000000
#define OFFS 21   // offv row stride (odd -> conflict-free)

__device__ __forceinline__ float bflo(unsigned w) { return __builtin_bit_cast(float, w << 16); }
__device__ __forceinline__ float bfhi(unsigned w) { return __builtin_bit_cast(float, w & 0xffff0000u); }
__device__ __forceinline__ unsigned short f2bf(float f) {   // RNE (prep kernels only)
    unsigned u = __builtin_bit_cast(unsigned, f);
    u += 0x7fffu + ((u >> 16) & 1u);
    return (unsigned short)(u >> 16);
}
// pack trunc-bf16(hi)<<16 | trunc-bf16(lo) in one v_perm_b32
__device__ __forceinline__ unsigned packbf(float lo, float hi) {
    return __builtin_amdgcn_perm(__builtin_bit_cast(unsigned, hi),
                                 __builtin_bit_cast(unsigned, lo), 0x07060302u);
}

// x[b][c][h][w] f32 -> xt[b][h][w][c] bf16
__global__ __launch_bounds__(256) void k_prep_xt(const float* __restrict__ x,
                                                 unsigned short* __restrict__ xt) {
    __shared__ float xs[64][129];
    const int bh = blockIdx.x;
    const int h = bh & 127, b = bh >> 7;
    const float* xr = x + ((size_t)b * 64 * 128 + h) * 128;
    for (int idx = threadIdx.x; idx < 8192; idx += 256) {
        int c = idx >> 7, w = idx & 127;
        xs[c][w] = xr[(size_t)c * 16384 + w];
    }
    __syncthreads();
    unsigned short* xto = xt + ((size_t)bh << 13);
    for (int j = threadIdx.x; j < 1024; j += 256) {
        int w = j >> 3, c0 = (j & 7) << 3;
        unsigned short tmp[8];
#pragma unroll
        for (int e = 0; e < 8; ++e) tmp[e] = f2bf(xs[c0 + e][w]);
        *(uint4*)(xto + w * 64 + c0) = *(const uint4*)tmp;
    }
}

// Fragment-ordered bf16 weights (see R2 comments).
__global__ void k_prep_w(const float* __restrict__ w_conv, const float* __restrict__ w_off,
                         unsigned short* __restrict__ w_m2, unsigned short* __restrict__ woff2) {
    int t = blockIdx.x * 256 + threadIdx.x;
    if (t < 36864) {
        int r = t & 511;
        int fid = t >> 9;
        int l15 = r >> 5, q4 = (r >> 3) & 3, e = t & 7;
        int chunk = fid & 1, of = (fid >> 1) & 3, n = fid >> 3;
        int o = of * 16 + l15, c = chunk * 32 + q4 * 8 + e;
        w_m2[t] = f2bf(w_conv[(o * 64 + c) * 9 + n]);
    }
    int t2 = t - 36864;
    if (t2 >= 0 && t2 < 18432) {
        int r = t2 & 511;
        int fid = t2 >> 9;
        int l15 = r >> 5, q4 = (r >> 3) & 3, e = t2 & 7;
        int kc = fid & 1, half = (fid >> 1) & 1, rj = fid >> 2;
        int k = half * 16 + l15, c = kc * 32 + q4 * 8 + e;
        woff2[t2] = (k < 18) ? f2bf(w_off[(k * 64 + c) * 9 + rj]) : (unsigned short)0;
    }
}

// One block = (b, h, wt): 64 pixels x 64 output channels. 4 waves.
__global__ __launch_bounds__(256, 2) void k_fused(
    const float* __restrict__ x, const unsigned short* __restrict__ xt,
    const unsigned short* __restrict__ w_m2, const unsigned short* __restrict__ woff2,
    const float* __restrict__ b_off, float* __restrict__ out) {

    __shared__ __align__(16) unsigned char raw[420 * 128];   // 6 rows x 70 cols x 64ch bf16, swizzled
    __shared__ int   atab[9][64][4];
    __shared__ float gtab[9][64][4];
    __shared__ float offv[64 * OFFS];
    __shared__ int   sfb;

    const int wk = ((blockIdx.x & 7) << 8) + (blockIdx.x >> 3);   // XCD swizzle
    const int b = wk >> 8, h = (wk >> 1) & 127, wt = (wk & 1) << 6;

    const int tid  = threadIdx.x;
    const int lane = tid & 63, wid = tid >> 6;
    const int l15  = lane & 15, q4 = lane >> 4;
    const int lofs = ((l15 << 2) + q4) << 3;
    const int px   = wid * 16 + l15;

    const unsigned short* xtb = xt + ((size_t)b << 20);

    if (tid == 0) sfb = 0;

    // ---- stage window ----
    for (int idx = tid; idx < 3360; idx += 256) {
        int rec = idx >> 3, cc = idx & 7;
        int row = rec / 70, col = rec - row * 70;
        int xr = h - 2 + row, xc = wt - 3 + col;
        uint4 v = make_uint4(0, 0, 0, 0);
        if (xr >= 0 && xr < 128 && xc >= 0 && xc < 128)
            v = *(const uint4*)(xtb + ((((size_t)xr << 7) + xc) << 6) + (cc << 3));
        *(uint4*)(raw + (rec << 7) + ((cc ^ (col & 7)) << 4)) = v;
    }
    __syncthreads();

    // ---- Phase A: offset conv via MFMA ----
    {
        f32x4 o0 = {0.f, 0.f, 0.f, 0.f}, o1 = {0.f, 0.f, 0.f, 0.f};
#pragma unroll
        for (int rj = 0; rj < 9; ++rj) {
            const int dr = rj / 3, dj = rj % 3;
            const int colw = px + dj + 2;
            const int recb = (dr + 1) * 70 + colw;
            const int swz  = colw & 7;
#pragma unroll
            for (int kc = 0; kc < 2; ++kc) {
                bf16x8 bfrag = *(const bf16x8*)(raw + (recb << 7) + ((((kc << 2) + q4) ^ swz) << 4));
                bf16x8 a0 = *(const bf16x8*)(woff2 + ((((rj * 2 + 0) << 1) + kc) << 9) + lofs);
                bf16x8 a1 = *(const bf16x8*)(woff2 + ((((rj * 2 + 1) << 1) + kc) << 9) + lofs);
                o0 = MFMA16(a0, bfrag, o0);
                o1 = MFMA16(a1, bfrag, o1);
            }
        }
#pragma unroll
        for (int rg = 0; rg < 4; ++rg) {
            int o = q4 * 4 + rg;
            offv[px * OFFS + o] = o0[rg] + b_off[o];
            int o1i = 16 + o;
            if (o1i < 18) offv[px * OFFS + o1i] = o1[rg] + b_off[o1i];
        }
    }
    __syncthreads();

    // ---- Phase B: corner entries + weights; set sfb if any global fallback ----
    for (int idx = tid; idx < 576; idx += 256) {
        const int n = idx >> 6, p = idx & 63;
        float ox = offv[p * OFFS + n], oy = offv[p * OFFS + 9 + n];
        float pxf = ox + (float)(n / 3 - 1) + (float)(h + 1);
        float pyf = oy + (float)(n % 3 - 1) + (float)(wt + p + 1);
        float fx = floorf(pxf), fy = floorf(pyf);
        float fxc  = fminf(fmaxf(fx, 0.f), 129.f);
        float fyc  = fminf(fmaxf(fy, 0.f), 129.f);
        float fxc1 = fminf(fmaxf(fx + 1.f, 0.f), 129.f);
        float fyc1 = fminf(fmaxf(fy + 1.f, 0.f), 129.f);
        int qltx = (int)fxc, qlty = (int)fyc, qrbx = (int)fxc1, qrby = (int)fyc1;
        pxf = fminf(fmaxf(pxf, 0.f), 129.f);
        pyf = fminf(fmaxf(pyf, 0.f), 129.f);
        float glt = (1.f + (fxc  - pxf)) * (1.f + (fyc  - pyf));
        float grb = (1.f - (fxc1 - pxf)) * (1.f - (fyc1 - pyf));
        float glb = (1.f + (fxc  - pxf)) * (1.f - (fyc1 - pyf));
        float grt = (1.f - (fxc1 - pxf)) * (1.f + (fyc  - pyf));
        bool vlx = (qltx >= 1) & (qltx <= 128), vly = (qlty >= 1) & (qlty <= 128);
        bool vrx = (qrbx >= 1) & (qrbx <= 128), vry = (qrby >= 1) & (qrby <= 128);

        auto enc = [&](int qx, int qy, bool val) -> int {
            if (!val) return 0;
            int wr = qx - h + 1;
            int wc = qy - wt + 2;
            if (wr >= 0 && wr < 6 && wc >= 0 && wc < 70)
                return ((wr * 70 + wc) << 7) | ((wc & 7) << 4);
            return GTAG | ((((qx - 1) << 7) + (qy - 1)) << 6);
        };
        int a0 = enc(qltx, qlty, vlx & vly);
        int a1 = enc(qrbx, qrby, vrx & vry);
        int a2 = enc(qltx, qrby, vlx & vry);
        int a3 = enc(qrbx, qlty, vrx & vly);
        if ((a0 | a1 | a2 | a3) & GTAG) sfb = 1;
        if (!(vlx & vly)) glt = 0.f;
        if (!(vrx & vry)) grb = 0.f;
        if (!(vlx & vry)) glb = 0.f;
        if (!(vrx & vly)) grt = 0.f;
        *(int4*)&atab[n][p][0]   = make_int4(a0, a1, a2, a3);
        *(float4*)&gtab[n][p][0] = make_float4(glt, grb, glb, grt);
    }
    __syncthreads();

    // ---- residual prefetch (16 regs, in flight under the tap loop) ----
    const size_t obase = ((size_t)b * 64 * 128 + h) * 128 + wt + px;
    float xres[4][4];
#pragma unroll
    for (int of = 0; of < 4; ++of)
#pragma unroll
        for (int rg = 0; rg < 4; ++rg)
            xres[of][rg] = x[obase + (size_t)(of * 16 + q4 * 4 + rg) * 16384];

    f32x4 acc[4];
#pragma unroll
    for (int of = 0; of < 4; ++of) acc[of] = (f32x4){0.f, 0.f, 0.f, 0.f};

    if (!sfb) {
        // ================= FAST PATH: zero branches, fully unrolled =================
#pragma unroll
        for (int n = 0; n < 9; ++n) {
            const int4   av = *(const int4*)&atab[n][px][0];
            const float4 gv = *(const float4*)&gtab[n][px][0];
            const int ee[4] = {av.x, av.y, av.z, av.w};
            uint4 clo[4], chi[4];
#pragma unroll
            for (int j = 0; j < 4; ++j) {
                const unsigned char* lp = raw + (ee[j] & ~127);
                int sl = ((q4 ^ (ee[j] >> 4)) & 7) << 4;
                clo[j] = *(const uint4*)(lp + sl);
                chi[j] = *(const uint4*)(lp + (sl ^ 64));
            }
            unsigned owl[4], owh[4];
            {
                const unsigned* p0 = (const unsigned*)&clo[0];
                const unsigned* p1 = (const unsigned*)&clo[1];
                const unsigned* p2 = (const unsigned*)&clo[2];
                const unsigned* p3 = (const unsigned*)&clo[3];
                const unsigned* h0 = (const unsigned*)&chi[0];
                const unsigned* h1 = (const unsigned*)&chi[1];
                const unsigned* h2 = (const unsigned*)&chi[2];
                const unsigned* h3 = (const unsigned*)&chi[3];
#pragma unroll
                for (int d = 0; d < 4; ++d) {
                    float flo = fmaf(gv.x, bflo(p0[d]), fmaf(gv.y, bflo(p1[d]), fmaf(gv.z, bflo(p2[d]), gv.w * bflo(p3[d]))));
                    float fhi = fmaf(gv.x, bfhi(p0[d]), fmaf(gv.y, bfhi(p1[d]), fmaf(gv.z, bfhi(p2[d]), gv.w * bfhi(p3[d]))));
                    owl[d] = packbf(flo, fhi);
                    float glo = fmaf(gv.x, bflo(h0[d]), fmaf(gv.y, bflo(h1[d]), fmaf(gv.z, bflo(h2[d]), gv.w * bflo(h3[d]))));
                    float ghi = fmaf(gv.x, bfhi(h0[d]), fmaf(gv.y, bfhi(h1[d]), fmaf(gv.z, bfhi(h2[d]), gv.w * bfhi(h3[d]))));
                    owh[d] = packbf(glo, ghi);
                }
            }
            bf16x8 bfr0 = *(const bf16x8*)&owl[0];
            bf16x8 bfr1 = *(const bf16x8*)&owh[0];
            const unsigned short* wn = w_m2 + (n << 12);
#pragma unroll
            for (int of = 0; of < 4; ++of) {
                bf16x8 a0 = *(const bf16x8*)(wn + (((of << 1) + 0) << 9) + lofs);
                bf16x8 a1 = *(const bf16x8*)(wn + (((of << 1) + 1) << 9) + lofs);
                acc[of] = MFMA16(a0, bfr0, acc[of]);
                acc[of] = MFMA16(a1, bfr1, acc[of]);
            }
        }
    } else {
        // ================= SLOW PATH: rare (any out-of-window corner) =================
        for (int n = 0; n < 9; ++n) {
            const int4   av = *(const int4*)&atab[n][px][0];
            const float4 gv = *(const float4*)&gtab[n][px][0];
            const int ee[4] = {av.x, av.y, av.z, av.w};
            uint4 clo[4], chi[4];
#pragma unroll
            for (int j = 0; j < 4; ++j) {
                int e = ee[j];
                if (e & GTAG) {
                    const unsigned short* gp = xtb + (e & (GTAG - 1));
                    clo[j] = *(const uint4*)(gp + (q4 << 3));
                    chi[j] = *(const uint4*)(gp + (q4 << 3) + 32);
                } else {
                    const unsigned char* lp = raw + (e & ~127);
                    int sl = ((q4 ^ (e >> 4)) & 7) << 4;
                    clo[j] = *(const uint4*)(lp + sl);
                    chi[j] = *(const uint4*)(lp + (sl ^ 64));
                }
            }
            unsigned owl[4], owh[4];
            {
                const unsigned* p0 = (const unsigned*)&clo[0];
                const unsigned* p1 = (const unsigned*)&clo[1];
                const unsigned* p2 = (const unsigned*)&clo[2];
                const unsigned* p3 = (const unsigned*)&clo[3];
                const unsigned* h0 = (const unsigned*)&chi[0];
                const unsigned* h1 = (const unsigned*)&chi[1];
                const unsigned* h2 = (const unsigned*)&chi[2];
                const unsigned* h3 = (const unsigned*)&chi[3];
#pragma unroll
                for (int d = 0; d < 4; ++d) {
                    float flo = fmaf(gv.x, bflo(p0[d]), fmaf(gv.y, bflo(p1[d]), fmaf(gv.z, bflo(p2[d]), gv.w * bflo(p3[d]))));
                    float fhi = fmaf(gv.x, bfhi(p0[d]), fmaf(gv.y, bfhi(p1[d]), fmaf(gv.z, bfhi(p2[d]), gv.w * bfhi(p3[d]))));
                    owl[d] = packbf(flo, fhi);
                    float glo = fmaf(gv.x, bflo(h0[d]), fmaf(gv.y, bflo(h1[d]), fmaf(gv.z, bflo(h2[d]), gv.w * bflo(h3[d]))));
                    float ghi = fmaf(gv.x, bfhi(h0[d]), fmaf(gv.y, bfhi(h1[d]), fmaf(gv.z, bfhi(h2[d]), gv.w * bfhi(h3[d]))));
                    owh[d] = packbf(glo, ghi);
                }
            }
            bf16x8 bfr0 = *(const bf16x8*)&owl[0];
            bf16x8 bfr1 = *(const bf16x8*)&owh[0];
            const unsigned short* wn = w_m2 + (n << 12);
#pragma unroll
            for (int of = 0; of < 4; ++of) {
                bf16x8 a0 = *(const bf16x8*)(wn + (((of << 1) + 0) << 9) + lofs);
                bf16x8 a1 = *(const bf16x8*)(wn + (((of << 1) + 1) << 9) + lofs);
                acc[of] = MFMA16(a0, bfr0, acc[of]);
                acc[of] = MFMA16(a1, bfr1, acc[of]);
            }
        }
    }

    // ---- Epilogue ----
#pragma unroll
    for (int of = 0; of < 4; ++of)
#pragma unroll
        for (int rg = 0; rg < 4; ++rg)
            out[obase + (size_t)(of * 16 + q4 * 4 + rg) * 16384] = acc[of][rg] + xres[of][rg];
}

extern "C" void kernel_launch(void* const* d_in, const int* in_sizes, int n_in,
                              void* d_out, int out_size, void* d_ws, size_t ws_size,
                              hipStream_t stream) {
    const float* x      = (const float*)d_in[0];
    const float* w_off  = (const float*)d_in[1];
    const float* b_off  = (const float*)d_in[2];
    const float* w_conv = (const float*)d_in[3];

    unsigned short* xt    = (unsigned short*)d_ws;
    unsigned short* w_m2  = xt + (size_t)8 * 128 * 128 * 64;
    unsigned short* woff2 = w_m2 + 9 * 64 * 64;

    hipLaunchKernelGGL(k_prep_xt, dim3(1024), dim3(256), 0, stream, x, xt);
    hipLaunchKernelGGL(k_prep_w,  dim3(216),  dim3(256), 0, stream, w_conv, w_off, w_m2, woff2);
    hipLaunchKernelGGL(k_fused,   dim3(2048), dim3(256), 0, stream,
                       x, xt, w_m2, woff2, b_off, (float*)d_out);
}

// Round 5
// 93.239 us; speedup vs baseline: 5.6398x; 1.0448x over previous
//
#include <hip/hip_runtime.h>

// DeformConv2dBlock on gfx950: B=8, C=64, H=W=128, N=9 taps, pad=1.
// R4: fp16 pipeline — packed v_pk_fma_f16 blend (32 ops/tap vs ~104), pre-packed
// half2 bilinear weights, double-buffered register prefetch of GEMM weights.
// Structure (window/tables/fast-slow split) from R3.

typedef _Float16 h2    __attribute__((ext_vector_type(2)));
typedef _Float16 f16x8 __attribute__((ext_vector_type(8)));
typedef float    f32x4 __attribute__((ext_vector_type(4)));

#define MFMAH(a, b, c) __builtin_amdgcn_mfma_f32_16x16x32_f16(a, b, c, 0, 0, 0)
#define GTAG 0x40000000
#define OFFS 21   // offv row stride (odd -> conflict-free)

__device__ __forceinline__ h2 bch2(unsigned u) { return __builtin_bit_cast(h2, u); }
__device__ __forceinline__ unsigned bcu(h2 v) { return __builtin_bit_cast(unsigned, v); }
__device__ __forceinline__ unsigned short f2h(float f) {
    return __builtin_bit_cast(unsigned short, (_Float16)f);
}

// x[b][c][h][w] f32 -> xt[b][h][w][c] fp16
__global__ __launch_bounds__(256) void k_prep_xt(const float* __restrict__ x,
                                                 unsigned short* __restrict__ xt) {
    __shared__ float xs[64][129];
    const int bh = blockIdx.x;
    const int h = bh & 127, b = bh >> 7;
    const float* xr = x + ((size_t)b * 64 * 128 + h) * 128;
    for (int idx = threadIdx.x; idx < 8192; idx += 256) {
        int c = idx >> 7, w = idx & 127;
        xs[c][w] = xr[(size_t)c * 16384 + w];
    }
    __syncthreads();
    unsigned short* xto = xt + ((size_t)bh << 13);
    for (int j = threadIdx.x; j < 1024; j += 256) {
        int w = j >> 3, c0 = (j & 7) << 3;
        unsigned short tmp[8];
#pragma unroll
        for (int e = 0; e < 8; ++e) tmp[e] = f2h(xs[c0 + e][w]);
        *(uint4*)(xto + w * 64 + c0) = *(const uint4*)tmp;
    }
}

// Fragment-ordered fp16 weights (layout as R3).
__global__ void k_prep_w(const float* __restrict__ w_conv, const float* __restrict__ w_off,
                         unsigned short* __restrict__ w_m2, unsigned short* __restrict__ woff2) {
    int t = blockIdx.x * 256 + threadIdx.x;
    if (t < 36864) {
        int r = t & 511;
        int fid = t >> 9;
        int l15 = r >> 5, q4 = (r >> 3) & 3, e = t & 7;
        int chunk = fid & 1, of = (fid >> 1) & 3, n = fid >> 3;
        int o = of * 16 + l15, c = chunk * 32 + q4 * 8 + e;
        w_m2[t] = f2h(w_conv[(o * 64 + c) * 9 + n]);
    }
    int t2 = t - 36864;
    if (t2 >= 0 && t2 < 18432) {
        int r = t2 & 511;
        int fid = t2 >> 9;
        int l15 = r >> 5, q4 = (r >> 3) & 3, e = t2 & 7;
        int kc = fid & 1, half = (fid >> 1) & 1, rj = fid >> 2;
        int k = half * 16 + l15, c = kc * 32 + q4 * 8 + e;
        woff2[t2] = (k < 18) ? f2h(w_off[(k * 64 + c) * 9 + rj]) : (unsigned short)0;
    }
}

// One block = (b, h, wt): 64 pixels x 64 output channels. 4 waves.
__global__ __launch_bounds__(256, 2) void k_fused(
    const float* __restrict__ x, const unsigned short* __restrict__ xt,
    const unsigned short* __restrict__ w_m2, const unsigned short* __restrict__ woff2,
    const float* __restrict__ b_off, float* __restrict__ out) {

    __shared__ __align__(16) unsigned char raw[420 * 128];   // 6 rows x 70 cols x 64ch fp16, swizzled
    __shared__ int   atab[9][64][4];
    __shared__ uint4 gtab[9][64];     // 4 packed half2 (g,g) per (tap,pixel)
    __shared__ float offv[64 * OFFS];
    __shared__ int   sfb;

    const int wk = ((blockIdx.x & 7) << 8) + (blockIdx.x >> 3);   // XCD swizzle
    const int b = wk >> 8, h = (wk >> 1) & 127, wt = (wk & 1) << 6;

    const int tid  = threadIdx.x;
    const int lane = tid & 63, wid = tid >> 6;
    const int l15  = lane & 15, q4 = lane >> 4;
    const int lofs = ((l15 << 2) + q4) << 3;
    const int px   = wid * 16 + l15;

    const unsigned short* xtb = xt + ((size_t)b << 20);

    if (tid == 0) sfb = 0;

    // ---- stage window: xt rows [h-2,h+3], cols [wt-3,wt+66], zero-filled, swizzled ----
    for (int idx = tid; idx < 3360; idx += 256) {
        int rec = idx >> 3, cc = idx & 7;
        int row = rec / 70, col = rec - row * 70;
        int xr = h - 2 + row, xc = wt - 3 + col;
        uint4 v = make_uint4(0, 0, 0, 0);
        if (xr >= 0 && xr < 128 && xc >= 0 && xc < 128)
            v = *(const uint4*)(xtb + ((((size_t)xr << 7) + xc) << 6) + (cc << 3));
        *(uint4*)(raw + (rec << 7) + ((cc ^ (col & 7)) << 4)) = v;
    }
    __syncthreads();

    // ---- Phase A: offset conv via fp16 MFMA ----
    {
        f32x4 o0 = {0.f, 0.f, 0.f, 0.f}, o1 = {0.f, 0.f, 0.f, 0.f};
#pragma unroll
        for (int rj = 0; rj < 9; ++rj) {
            const int dr = rj / 3, dj = rj % 3;
            const int colw = px + dj + 2;
            const int recb = (dr + 1) * 70 + colw;
            const int swz  = colw & 7;
#pragma unroll
            for (int kc = 0; kc < 2; ++kc) {
                f16x8 bfrag = *(const f16x8*)(raw + (recb << 7) + ((((kc << 2) + q4) ^ swz) << 4));
                f16x8 a0 = *(const f16x8*)((const _Float16*)woff2 + ((((rj * 2 + 0) << 1) + kc) << 9) + lofs);
                f16x8 a1 = *(const f16x8*)((const _Float16*)woff2 + ((((rj * 2 + 1) << 1) + kc) << 9) + lofs);
                o0 = MFMAH(a0, bfrag, o0);
                o1 = MFMAH(a1, bfrag, o1);
            }
        }
#pragma unroll
        for (int rg = 0; rg < 4; ++rg) {
            int o = q4 * 4 + rg;
            offv[px * OFFS + o] = o0[rg] + b_off[o];
            int o1i = 16 + o;
            if (o1i < 18) offv[px * OFFS + o1i] = o1[rg] + b_off[o1i];
        }
    }
    __syncthreads();

    // ---- Phase B: corner entries + packed bilinear weights; sfb on fallback ----
    for (int idx = tid; idx < 576; idx += 256) {
        const int n = idx >> 6, p = idx & 63;
        float ox = offv[p * OFFS + n], oy = offv[p * OFFS + 9 + n];
        float pxf = ox + (float)(n / 3 - 1) + (float)(h + 1);
        float pyf = oy + (float)(n % 3 - 1) + (float)(wt + p + 1);
        float fx = floorf(pxf), fy = floorf(pyf);
        float fxc  = fminf(fmaxf(fx, 0.f), 129.f);
        float fyc  = fminf(fmaxf(fy, 0.f), 129.f);
        float fxc1 = fminf(fmaxf(fx + 1.f, 0.f), 129.f);
        float fyc1 = fminf(fmaxf(fy + 1.f, 0.f), 129.f);
        int qltx = (int)fxc, qlty = (int)fyc, qrbx = (int)fxc1, qrby = (int)fyc1;
        pxf = fminf(fmaxf(pxf, 0.f), 129.f);
        pyf = fminf(fmaxf(pyf, 0.f), 129.f);
        float glt = (1.f + (fxc  - pxf)) * (1.f + (fyc  - pyf));
        float grb = (1.f - (fxc1 - pxf)) * (1.f - (fyc1 - pyf));
        float glb = (1.f + (fxc  - pxf)) * (1.f - (fyc1 - pyf));
        float grt = (1.f - (fxc1 - pxf)) * (1.f + (fyc  - pyf));
        bool vlx = (qltx >= 1) & (qltx <= 128), vly = (qlty >= 1) & (qlty <= 128);
        bool vrx = (qrbx >= 1) & (qrbx <= 128), vry = (qrby >= 1) & (qrby <= 128);

        auto enc = [&](int qx, int qy, bool val) -> int {
            if (!val) return 0;
            int wr = qx - h + 1;
            int wc = qy - wt + 2;
            if (wr >= 0 && wr < 6 && wc >= 0 && wc < 70)
                return ((wr * 70 + wc) << 7) | ((wc & 7) << 4);
            return GTAG | ((((qx - 1) << 7) + (qy - 1)) << 6);
        };
        int a0 = enc(qltx, qlty, vlx & vly);
        int a1 = enc(qrbx, qrby, vrx & vry);
        int a2 = enc(qltx, qrby, vlx & vry);
        int a3 = enc(qrbx, qlty, vrx & vly);
        if ((a0 | a1 | a2 | a3) & GTAG) sfb = 1;
        if (!(vlx & vly)) glt = 0.f;
        if (!(vrx & vry)) grb = 0.f;
        if (!(vlx & vry)) glb = 0.f;
        if (!(vrx & vly)) grt = 0.f;
        auto pk = [](float g) -> unsigned {
            _Float16 t = (_Float16)g;
            h2 r = {t, t};
            return __builtin_bit_cast(unsigned, r);
        };
        *(int4*)&atab[n][p][0] = make_int4(a0, a1, a2, a3);
        gtab[n][p] = make_uint4(pk(glt), pk(grb), pk(glb), pk(grt));
    }
    __syncthreads();

    // ---- residual prefetch ----
    const size_t obase = ((size_t)b * 64 * 128 + h) * 128 + wt + px;
    float xres[4][4];
#pragma unroll
    for (int of = 0; of < 4; ++of)
#pragma unroll
        for (int rg = 0; rg < 4; ++rg)
            xres[of][rg] = x[obase + (size_t)(of * 16 + q4 * 4 + rg) * 16384];

    f32x4 acc[4];
#pragma unroll
    for (int of = 0; of < 4; ++of) acc[of] = (f32x4){0.f, 0.f, 0.f, 0.f};

    const _Float16* wmh = (const _Float16*)w_m2;
    // double-buffered weight fragments: [buf][kc][of]
    f16x8 wreg[2][2][4];
#pragma unroll
    for (int of = 0; of < 4; ++of) {
        wreg[0][0][of] = *(const f16x8*)(wmh + (((of << 1) + 0) << 9) + lofs);
        wreg[0][1][of] = *(const f16x8*)(wmh + (((of << 1) + 1) << 9) + lofs);
    }

    // packed fp16 bilinear blend -> two B fragments (channels 0-31, 32-63)
    auto blend = [&](const uint4* clo, const uint4* chi, uint4 gq, f16x8& bfr0, f16x8& bfr1) {
        h2 g0 = bch2(gq.x), g1 = bch2(gq.y), g2 = bch2(gq.z), g3 = bch2(gq.w);
        const unsigned* c0 = (const unsigned*)&clo[0];
        const unsigned* c1 = (const unsigned*)&clo[1];
        const unsigned* c2 = (const unsigned*)&clo[2];
        const unsigned* c3 = (const unsigned*)&clo[3];
        const unsigned* e0 = (const unsigned*)&chi[0];
        const unsigned* e1 = (const unsigned*)&chi[1];
        const unsigned* e2 = (const unsigned*)&chi[2];
        const unsigned* e3 = (const unsigned*)&chi[3];
        unsigned owl[4], owh[4];
#pragma unroll
        for (int d = 0; d < 4; ++d) {
            h2 sl = bch2(c0[d]) * g0;
            sl = __builtin_elementwise_fma(bch2(c1[d]), g1, sl);
            sl = __builtin_elementwise_fma(bch2(c2[d]), g2, sl);
            sl = __builtin_elementwise_fma(bch2(c3[d]), g3, sl);
            owl[d] = bcu(sl);
            h2 sh = bch2(e0[d]) * g0;
            sh = __builtin_elementwise_fma(bch2(e1[d]), g1, sh);
            sh = __builtin_elementwise_fma(bch2(e2[d]), g2, sh);
            sh = __builtin_elementwise_fma(bch2(e3[d]), g3, sh);
            owh[d] = bcu(sh);
        }
        bfr0 = __builtin_bit_cast(f16x8, *(const uint4*)owl);
        bfr1 = __builtin_bit_cast(f16x8, *(const uint4*)owh);
    };

    if (!sfb) {
        // ================= FAST PATH =================
#pragma unroll
        for (int n = 0; n < 9; ++n) {
            // prefetch next tap's weight fragments (global/L2) first
            if (n < 8) {
                const _Float16* wn1 = wmh + ((n + 1) << 12);
#pragma unroll
                for (int of = 0; of < 4; ++of) {
                    wreg[(n + 1) & 1][0][of] = *(const f16x8*)(wn1 + (((of << 1) + 0) << 9) + lofs);
                    wreg[(n + 1) & 1][1][of] = *(const f16x8*)(wn1 + (((of << 1) + 1) << 9) + lofs);
                }
            }
            const int4  av = *(const int4*)&atab[n][px][0];
            const uint4 gq = gtab[n][px];
            const int ee[4] = {av.x, av.y, av.z, av.w};
            uint4 clo[4], chi[4];
#pragma unroll
            for (int j = 0; j < 4; ++j) {
                const unsigned char* lp = raw + (ee[j] & ~127);
                int sl = ((q4 ^ (ee[j] >> 4)) & 7) << 4;
                clo[j] = *(const uint4*)(lp + sl);
                chi[j] = *(const uint4*)(lp + (sl ^ 64));
            }
            f16x8 bfr0, bfr1;
            blend(clo, chi, gq, bfr0, bfr1);
#pragma unroll
            for (int of = 0; of < 4; ++of) {
                acc[of] = MFMAH(wreg[n & 1][0][of], bfr0, acc[of]);
                acc[of] = MFMAH(wreg[n & 1][1][of], bfr1, acc[of]);
            }
        }
    } else {
        // ================= SLOW PATH (rare) =================
        for (int n = 0; n < 9; ++n) {
            const int4  av = *(const int4*)&atab[n][px][0];
            const uint4 gq = gtab[n][px];
            const int ee[4] = {av.x, av.y, av.z, av.w};
            uint4 clo[4], chi[4];
#pragma unroll
            for (int j = 0; j < 4; ++j) {
                int e = ee[j];
                if (e & GTAG) {
                    const unsigned short* gp = xtb + (e & (GTAG - 1));
                    clo[j] = *(const uint4*)(gp + (q4 << 3));
                    chi[j] = *(const uint4*)(gp + (q4 << 3) + 32);
                } else {
                    const unsigned char* lp = raw + (e & ~127);
                    int sl = ((q4 ^ (e >> 4)) & 7) << 4;
                    clo[j] = *(const uint4*)(lp + sl);
                    chi[j] = *(const uint4*)(lp + (sl ^ 64));
                }
            }
            f16x8 bfr0, bfr1;
            blend(clo, chi, gq, bfr0, bfr1);
            const _Float16* wn = wmh + (n << 12);
#pragma unroll
            for (int of = 0; of < 4; ++of) {
                f16x8 a0 = *(const f16x8*)(wn + (((of << 1) + 0) << 9) + lofs);
                f16x8 a1 = *(const f16x8*)(wn + (((of << 1) + 1) << 9) + lofs);
                acc[of] = MFMAH(a0, bfr0, acc[of]);
                acc[of] = MFMAH(a1, bfr1, acc[of]);
            }
        }
    }

    // ---- Epilogue ----
#pragma unroll
    for (int of = 0; of < 4; ++of)
#pragma unroll
        for (int rg = 0; rg < 4; ++rg)
            out[obase + (size_t)(of * 16 + q4 * 4 + rg) * 16384] = acc[of][rg] + xres[of][rg];
}

extern "C" void kernel_launch(void* const* d_in, const int* in_sizes, int n_in,
                              void* d_out, int out_size, void* d_ws, size_t ws_size,
                              hipStream_t stream) {
    const float* x      = (const float*)d_in[0];
    const float* w_off  = (const float*)d_in[1];
    const float* b_off  = (const float*)d_in[2];
    const float* w_conv = (const float*)d_in[3];

    unsigned short* xt    = (unsigned short*)d_ws;
    unsigned short* w_m2  = xt + (size_t)8 * 128 * 128 * 64;
    unsigned short* woff2 = w_m2 + 9 * 64 * 64;

    hipLaunchKernelGGL(k_prep_xt, dim3(1024), dim3(256), 0, stream, x, xt);
    hipLaunchKernelGGL(k_prep_w,  dim3(216),  dim3(256), 0, stream, w_conv, w_off, w_m2, woff2);
    hipLaunchKernelGGL(k_fused,   dim3(2048), dim3(256), 0, stream,
                       x, xt, w_m2, woff2, b_off, (float*)d_out);
}

// Round 6
// 84.546 us; speedup vs baseline: 6.2197x; 1.1028x over previous
//
#include <hip/hip_runtime.h>

// DeformConv2dBlock on gfx950: B=8, C=64, H=W=128, N=9 taps, pad=1.
// R5: rolling 4-row LDS ring (35.8KB) -> 4 blocks/CU; inline corner math from
// register-held offsets (no atab/gtab); register row prefetch between tap groups.

typedef _Float16 h2    __attribute__((ext_vector_type(2)));
typedef _Float16 f16x8 __attribute__((ext_vector_type(8)));
typedef float    f32x4 __attribute__((ext_vector_type(4)));

#define MFMAH(a, b, c) __builtin_amdgcn_mfma_f32_16x16x32_f16(a, b, c, 0, 0, 0)

__device__ __forceinline__ unsigned short f2h(float f) {
    return __builtin_bit_cast(unsigned short, (_Float16)f);
}
__device__ __forceinline__ float h2f_bits(unsigned u) {
    return (float)__builtin_bit_cast(_Float16, (unsigned short)(u & 0xffffu));
}
__device__ __forceinline__ unsigned dup16(float g) {
    _Float16 t = (_Float16)g;
    h2 r = {t, t};
    return __builtin_bit_cast(unsigned, r);
}

// x[b][c][h][w] f32 -> xt[b][h][w][c] fp16
__global__ __launch_bounds__(256) void k_prep_xt(const float* __restrict__ x,
                                                 unsigned short* __restrict__ xt) {
    __shared__ float xs[64][129];
    const int bh = blockIdx.x;
    const int h = bh & 127, b = bh >> 7;
    const float* xr = x + ((size_t)b * 64 * 128 + h) * 128;
    for (int idx = threadIdx.x; idx < 8192; idx += 256) {
        int c = idx >> 7, w = idx & 127;
        xs[c][w] = xr[(size_t)c * 16384 + w];
    }
    __syncthreads();
    unsigned short* xto = xt + ((size_t)bh << 13);
    for (int j = threadIdx.x; j < 1024; j += 256) {
        int w = j >> 3, c0 = (j & 7) << 3;
        unsigned short tmp[8];
#pragma unroll
        for (int e = 0; e < 8; ++e) tmp[e] = f2h(xs[c0 + e][w]);
        *(uint4*)(xto + w * 64 + c0) = *(const uint4*)tmp;
    }
}

// Fragment-ordered fp16 weights (layout as R3/R4).
__global__ void k_prep_w(const float* __restrict__ w_conv, const float* __restrict__ w_off,
                         unsigned short* __restrict__ w_m2, unsigned short* __restrict__ woff2) {
    int t = blockIdx.x * 256 + threadIdx.x;
    if (t < 36864) {
        int r = t & 511;
        int fid = t >> 9;
        int l15 = r >> 5, q4 = (r >> 3) & 3, e = t & 7;
        int chunk = fid & 1, of = (fid >> 1) & 3, n = fid >> 3;
        int o = of * 16 + l15, c = chunk * 32 + q4 * 8 + e;
        w_m2[t] = f2h(w_conv[(o * 64 + c) * 9 + n]);
    }
    int t2 = t - 36864;
    if (t2 >= 0 && t2 < 18432) {
        int r = t2 & 511;
        int fid = t2 >> 9;
        int l15 = r >> 5, q4 = (r >> 3) & 3, e = t2 & 7;
        int kc = fid & 1, half = (fid >> 1) & 1, rj = fid >> 2;
        int k = half * 16 + l15, c = kc * 32 + q4 * 8 + e;
        woff2[t2] = (k < 18) ? f2h(w_off[(k * 64 + c) * 9 + rj]) : (unsigned short)0;
    }
}

// One block = (b, h, wt): 64 pixels x 64 output channels. 4 waves.
__global__ __launch_bounds__(256, 4) void k_fused(
    const float* __restrict__ x, const unsigned short* __restrict__ xt,
    const unsigned short* __restrict__ w_m2, const unsigned short* __restrict__ woff2,
    const float* __restrict__ b_off, float* __restrict__ out) {

    __shared__ __align__(16) unsigned char raw[4 * 70 * 128];   // 4-slot row ring, swizzled
    __shared__ __align__(16) _Float16 offv[64 * 24];            // [px][24] f16: k=0..8 ox, 9..17 oy
    __shared__ int sfb;

    const int wk = ((blockIdx.x & 7) << 8) + (blockIdx.x >> 3);   // XCD swizzle
    const int b = wk >> 8, h = (wk >> 1) & 127, wt = (wk & 1) << 6;

    const int tid  = threadIdx.x;
    const int lane = tid & 63, wid = tid >> 6;
    const int l15  = lane & 15, q4 = lane >> 4;
    const int lofs = ((l15 << 2) + q4) << 3;
    const int px   = wid * 16 + l15;

    const unsigned short* xtb = xt + ((size_t)b << 20);
    const _Float16* wmh  = (const _Float16*)w_m2;

    if (tid == 0) sfb = 0;

    // ---- initial staging: unpadded rows h-2..h+1 -> slots 0..3 ----
    for (int idx = tid; idx < 2240; idx += 256) {
        int rec = idx >> 3, cc = idx & 7;
        int rl = rec / 70, col = rec - rl * 70;
        int xr = h - 2 + rl, xc = wt - 3 + col;
        uint4 v = make_uint4(0, 0, 0, 0);
        if (xr >= 0 && xr < 128 && xc >= 0 && xc < 128)
            v = *(const uint4*)(xtb + ((((size_t)xr << 7) + xc) << 6) + (cc << 3));
        *(uint4*)(raw + (rec << 7) + ((cc ^ (col & 7)) << 4)) = v;
    }
    __syncthreads();

    // ---- Phase A: offset conv via fp16 MFMA (reads slots 1..3) ----
    {
        f32x4 o0 = {0.f, 0.f, 0.f, 0.f}, o1 = {0.f, 0.f, 0.f, 0.f};
#pragma unroll
        for (int rj = 0; rj < 9; ++rj) {
            const int dr = rj / 3, dj = rj % 3;
            const int colw = px + dj + 2;
            const int recb = (dr + 1) * 70 + colw;
            const int swz  = colw & 7;
#pragma unroll
            for (int kc = 0; kc < 2; ++kc) {
                f16x8 bfrag = *(const f16x8*)(raw + (recb << 7) + ((((kc << 2) + q4) ^ swz) << 4));
                f16x8 a0 = *(const f16x8*)((const _Float16*)woff2 + ((((rj * 2 + 0) << 1) + kc) << 9) + lofs);
                f16x8 a1 = *(const f16x8*)((const _Float16*)woff2 + ((((rj * 2 + 1) << 1) + kc) << 9) + lofs);
                o0 = MFMAH(a0, bfrag, o0);
                o1 = MFMAH(a1, bfrag, o1);
            }
        }
        float4 bo = *(const float4*)(b_off + (q4 << 2));
        float2 bo2 = *(const float2*)(b_off + 16);
        const float bov[4] = {bo.x, bo.y, bo.z, bo.w};
#pragma unroll
        for (int rg = 0; rg < 4; ++rg) {
            int o = (q4 << 2) + rg;
            offv[px * 24 + o] = (_Float16)(o0[rg] + bov[rg]);
            if (q4 == 0 && rg < 2) offv[px * 24 + 16 + rg] = (_Float16)(o1[rg] + (rg ? bo2.y : bo2.x));
        }
    }
    __syncthreads();

    // ---- Phase B-lite: set sfb if any clipped corner leaves ring/col window ----
    for (int idx = tid; idx < 576; idx += 256) {
        const int n = idx >> 6, p = idx & 63;
        const int dr = n / 3, dj = n % 3;
        float ox = (float)offv[p * 24 + n], oy = (float)offv[p * 24 + 9 + n];
        float pxf = (float)(h + dr) + ox, pyf = (float)(wt + p + dj) + oy;
        float fx = floorf(pxf), fy = floorf(pyf);
        int qx0 = (int)fminf(fmaxf(fx, 0.f), 129.f);
        int qx1 = (int)fminf(fmaxf(fx + 1.f, 0.f), 129.f);
        int qy0 = (int)fminf(fmaxf(fy, 0.f), 129.f);
        int qy1 = (int)fminf(fmaxf(fy + 1.f, 0.f), 129.f);
        int r0 = qx0 - h - dr, r1 = qx1 - h - dr;
        int c0 = qy0 - wt + 2, c1 = qy1 - wt + 2;
        bool oow = (r0 < -1) | (r0 > 2) | (r1 < -1) | (r1 > 2) |
                   (c0 < 0) | (c0 >= 70) | (c1 < 0) | (c1 >= 70);
        if (oow) sfb = 1;
    }
    __syncthreads();
    const bool slow = (sfb != 0);

    f32x4 acc[4];
#pragma unroll
    for (int of = 0; of < 4; ++of) acc[of] = (f32x4){0.f, 0.f, 0.f, 0.f};

    // packed fp16 blend -> two B fragments
    auto blend = [&](const uint4* clo, const uint4* chi, uint4 gq, f16x8& bfr0, f16x8& bfr1) {
        h2 g0 = __builtin_bit_cast(h2, gq.x), g1 = __builtin_bit_cast(h2, gq.y);
        h2 g2 = __builtin_bit_cast(h2, gq.z), g3 = __builtin_bit_cast(h2, gq.w);
        const unsigned* c0 = (const unsigned*)&clo[0];
        const unsigned* c1 = (const unsigned*)&clo[1];
        const unsigned* c2 = (const unsigned*)&clo[2];
        const unsigned* c3 = (const unsigned*)&clo[3];
        const unsigned* e0 = (const unsigned*)&chi[0];
        const unsigned* e1 = (const unsigned*)&chi[1];
        const unsigned* e2 = (const unsigned*)&chi[2];
        const unsigned* e3 = (const unsigned*)&chi[3];
        unsigned owl[4], owh[4];
#pragma unroll
        for (int d = 0; d < 4; ++d) {
            h2 sl = __builtin_bit_cast(h2, c0[d]) * g0;
            sl = __builtin_elementwise_fma(__builtin_bit_cast(h2, c1[d]), g1, sl);
            sl = __builtin_elementwise_fma(__builtin_bit_cast(h2, c2[d]), g2, sl);
            sl = __builtin_elementwise_fma(__builtin_bit_cast(h2, c3[d]), g3, sl);
            owl[d] = __builtin_bit_cast(unsigned, sl);
            h2 sh = __builtin_bit_cast(h2, e0[d]) * g0;
            sh = __builtin_elementwise_fma(__builtin_bit_cast(h2, e1[d]), g1, sh);
            sh = __builtin_elementwise_fma(__builtin_bit_cast(h2, e2[d]), g2, sh);
            sh = __builtin_elementwise_fma(__builtin_bit_cast(h2, e3[d]), g3, sh);
            owh[d] = __builtin_bit_cast(unsigned, sh);
        }
        bfr0 = __builtin_bit_cast(f16x8, *(const uint4*)owl);
        bfr1 = __builtin_bit_cast(f16x8, *(const uint4*)owh);
    };

    if (!slow) {
        // ---- preload my pixel's 18 offsets (registers, const-indexed) ----
        const unsigned* op = (const unsigned*)(offv + px * 24);
        uint4 oA = *(const uint4*)op;
        uint4 oB = *(const uint4*)(op + 4);
        unsigned oC = op[8];
        const unsigned ow[9] = {oA.x, oA.y, oA.z, oA.w, oB.x, oB.y, oB.z, oB.w, oC};
#define OX(n) h2f_bits(ow[(n) >> 1] >> (((n) & 1) << 4))
#define OY(n) h2f_bits(ow[(9 + (n)) >> 1] >> (((9 + (n)) & 1) << 4))

        // ---- prefetch row h+2 into regs (written to slot 0 after dr=0) ----
        uint4 pf[3];
        int pcol[3], pcc[3];
#pragma unroll
        for (int k = 0; k < 3; ++k) {
            int idx = tid + (k << 8);
            bool v = idx < 560;
            int rec = idx >> 3;
            pcol[k] = v ? rec : 0;
            pcc[k]  = idx & 7;
            int xr = h + 2, xc = wt - 3 + pcol[k];
            uint4 vv = make_uint4(0, 0, 0, 0);
            if (v && xr < 128 && xc >= 0 && xc < 128)
                vv = *(const uint4*)(xtb + ((((size_t)xr << 7) + xc) << 6) + (pcc[k] << 3));
            if (!v) pcol[k] = -1;
            pf[k] = vv;
        }

#define TAP(n)                                                                           \
        {                                                                                \
            constexpr int dr = (n) / 3, dj = (n) % 3;                                    \
            const _Float16* wn = wmh + ((n) << 12);                                      \
            f16x8 wa0[4], wa1[4];                                                        \
            _Pragma("unroll")                                                            \
            for (int of = 0; of < 4; ++of) {                                             \
                wa0[of] = *(const f16x8*)(wn + (((of << 1) + 0) << 9) + lofs);           \
                wa1[of] = *(const f16x8*)(wn + (((of << 1) + 1) << 9) + lofs);           \
            }                                                                            \
            float ox = OX(n), oy = OY(n);                                                \
            float pxf = (float)(h + dr) + ox, pyf = (float)(wt + px + dj) + oy;          \
            float fx = floorf(pxf), fy = floorf(pyf);                                    \
            float qx0f = fminf(fmaxf(fx, 0.f), 129.f);                                   \
            float qx1f = fminf(fmaxf(fx + 1.f, 0.f), 129.f);                             \
            float qy0f = fminf(fmaxf(fy, 0.f), 129.f);                                   \
            float qy1f = fminf(fmaxf(fy + 1.f, 0.f), 129.f);                             \
            float pxc = fminf(fmaxf(pxf, 0.f), 129.f);                                   \
            float pyc = fminf(fmaxf(pyf, 0.f), 129.f);                                   \
            float ax0 = 1.f + (qx0f - pxc), ax1 = 1.f - (qx1f - pxc);                    \
            float ay0 = 1.f + (qy0f - pyc), ay1 = 1.f - (qy1f - pyc);                    \
            int s0 = ((((int)qx0f + 1 - h) & 3) * 70) << 7;                              \
            int s1 = ((((int)qx1f + 1 - h) & 3) * 70) << 7;                              \
            int c0 = (int)qy0f - wt + 2, c1 = (int)qy1f - wt + 2;                        \
            int blt = s0 + (c0 << 7), brb = s1 + (c1 << 7);                              \
            int blb = s0 + (c1 << 7), brt = s1 + (c0 << 7);                              \
            int z0 = ((q4 ^ c0) & 7) << 4, z1 = ((q4 ^ c1) & 7) << 4;                    \
            uint4 clo[4], chi[4];                                                        \
            clo[0] = *(const uint4*)(raw + blt + z0); chi[0] = *(const uint4*)(raw + blt + (z0 ^ 64)); \
            clo[1] = *(const uint4*)(raw + brb + z1); chi[1] = *(const uint4*)(raw + brb + (z1 ^ 64)); \
            clo[2] = *(const uint4*)(raw + blb + z1); chi[2] = *(const uint4*)(raw + blb + (z1 ^ 64)); \
            clo[3] = *(const uint4*)(raw + brt + z0); chi[3] = *(const uint4*)(raw + brt + (z0 ^ 64)); \
            uint4 gq = make_uint4(dup16(ax0 * ay0), dup16(ax1 * ay1),                    \
                                  dup16(ax0 * ay1), dup16(ax1 * ay0));                   \
            f16x8 bfr0, bfr1;                                                            \
            blend(clo, chi, gq, bfr0, bfr1);                                             \
            _Pragma("unroll")                                                            \
            for (int of = 0; of < 4; ++of) {                                             \
                acc[of] = MFMAH(wa0[of], bfr0, acc[of]);                                 \
                acc[of] = MFMAH(wa1[of], bfr1, acc[of]);                                 \
            }                                                                            \
        }

        TAP(0) TAP(1) TAP(2)
        __syncthreads();
#pragma unroll
        for (int k = 0; k < 3; ++k)
            if (pcol[k] >= 0)
                *(uint4*)(raw + ((0 * 70 + pcol[k]) << 7) + ((pcc[k] ^ (pcol[k] & 7)) << 4)) = pf[k];
        __syncthreads();
        // prefetch row h+3 (slot 1) during dr=1 compute
#pragma unroll
        for (int k = 0; k < 3; ++k) {
            int idx = tid + (k << 8);
            bool v = idx < 560;
            int rec = idx >> 3;
            pcol[k] = v ? rec : -1;
            pcc[k]  = idx & 7;
            int xr = h + 3, xc = wt - 3 + rec;
            uint4 vv = make_uint4(0, 0, 0, 0);
            if (v && xr < 128 && xc >= 0 && xc < 128)
                vv = *(const uint4*)(xtb + ((((size_t)xr << 7) + xc) << 6) + (pcc[k] << 3));
            pf[k] = vv;
        }
        TAP(3) TAP(4) TAP(5)
        __syncthreads();
#pragma unroll
        for (int k = 0; k < 3; ++k)
            if (pcol[k] >= 0)
                *(uint4*)(raw + ((1 * 70 + pcol[k]) << 7) + ((pcc[k] ^ (pcol[k] & 7)) << 4)) = pf[k];
        __syncthreads();
        TAP(6) TAP(7) TAP(8)
#undef TAP
#undef OX
#undef OY
    } else {
        // ---- SLOW PATH (~1% of blocks): all-global gather, offsets from LDS ----
        for (int n = 0; n < 9; ++n) {
            const int dr = n / 3, dj = n % 3;
            float ox = (float)offv[px * 24 + n], oy = (float)offv[px * 24 + 9 + n];
            float pxf = (float)(h + dr) + ox, pyf = (float)(wt + px + dj) + oy;
            float fx = floorf(pxf), fy = floorf(pyf);
            float qx0f = fminf(fmaxf(fx, 0.f), 129.f);
            float qx1f = fminf(fmaxf(fx + 1.f, 0.f), 129.f);
            float qy0f = fminf(fmaxf(fy, 0.f), 129.f);
            float qy1f = fminf(fmaxf(fy + 1.f, 0.f), 129.f);
            float pxc = fminf(fmaxf(pxf, 0.f), 129.f);
            float pyc = fminf(fmaxf(pyf, 0.f), 129.f);
            float ax0 = 1.f + (qx0f - pxc), ax1 = 1.f - (qx1f - pxc);
            float ay0 = 1.f + (qy0f - pyc), ay1 = 1.f - (qy1f - pyc);
            int qx[2] = {(int)qx0f, (int)qx1f};
            int qy[2] = {(int)qy0f, (int)qy1f};
            uint4 clo[4], chi[4];
            const int rsel[4] = {0, 1, 0, 1}, csel[4] = {0, 1, 1, 0};
#pragma unroll
            for (int j = 0; j < 4; ++j) {
                int rx = qx[rsel[j]], ry = qy[csel[j]];
                bool v = (rx >= 1) & (rx <= 128) & (ry >= 1) & (ry <= 128);
                clo[j] = make_uint4(0, 0, 0, 0);
                chi[j] = make_uint4(0, 0, 0, 0);
                if (v) {
                    const unsigned short* gp = xtb + ((((size_t)(rx - 1) << 7) + (ry - 1)) << 6);
                    clo[j] = *(const uint4*)(gp + (q4 << 3));
                    chi[j] = *(const uint4*)(gp + (q4 << 3) + 32);
                }
            }
            uint4 gq = make_uint4(dup16(ax0 * ay0), dup16(ax1 * ay1),
                                  dup16(ax0 * ay1), dup16(ax1 * ay0));
            f16x8 bfr0, bfr1;
            blend(clo, chi, gq, bfr0, bfr1);
            const _Float16* wn = wmh + (n << 12);
#pragma unroll
            for (int of = 0; of < 4; ++of) {
                f16x8 a0 = *(const f16x8*)(wn + (((of << 1) + 0) << 9) + lofs);
                f16x8 a1 = *(const f16x8*)(wn + (((of << 1) + 1) << 9) + lofs);
                acc[of] = MFMAH(a0, bfr0, acc[of]);
                acc[of] = MFMAH(a1, bfr1, acc[of]);
            }
        }
    }

    // ---- Epilogue: + residual ----
    const size_t obase = ((size_t)b * 64 * 128 + h) * 128 + wt + px;
#pragma unroll
    for (int of = 0; of < 4; ++of)
#pragma unroll
        for (int rg = 0; rg < 4; ++rg) {
            size_t a = obase + (size_t)((of << 4) + (q4 << 2) + rg) * 16384;
            out[a] = acc[of][rg] + x[a];
        }
}

extern "C" void kernel_launch(void* const* d_in, const int* in_sizes, int n_in,
                              void* d_out, int out_size, void* d_ws, size_t ws_size,
                              hipStream_t stream) {
    const float* x      = (const float*)d_in[0];
    const float* w_off  = (const float*)d_in[1];
    const float* b_off  = (const float*)d_in[2];
    const float* w_conv = (const float*)d_in[3];

    unsigned short* xt    = (unsigned short*)d_ws;
    unsigned short* w_m2  = xt + (size_t)8 * 128 * 128 * 64;
    unsigned short* woff2 = w_m2 + 9 * 64 * 64;

    hipLaunchKernelGGL(k_prep_xt, dim3(1024), dim3(256), 0, stream, x, xt);
    hipLaunchKernelGGL(k_prep_w,  dim3(216),  dim3(256), 0, stream, w_conv, w_off, w_m2, woff2);
    hipLaunchKernelGGL(k_fused,   dim3(2048), dim3(256), 0, stream,
                       x, xt, w_m2, woff2, b_off, (float*)d_out);
}